// Round 1
// baseline (3475.518 us; speedup 1.0000x reference)
//
#include <hip/hip_runtime.h>

#define NPTS 8192
#define SPTS 2048
#define KS 32
#define CF 64
#define BQ 4
#define FPS_T 512
#define PPT (NPTS / FPS_T)   // 16 points per thread
#define FPS_SHIFT 9          // log2(FPS_T)

#define OFF_GROUPED 24576                    // B*S*3
#define GROUPED_SZ  17563648                 // B*67*S*K
#define OFF_FPSIDX  (OFF_GROUPED + GROUPED_SZ)

// ---------------- FPS: one block per batch ----------------
__global__ __launch_bounds__(FPS_T)
void fps_kernel(const float* __restrict__ xyz, float* __restrict__ out)
{
#pragma clang fp contract(off)
    __shared__ unsigned long long slots[16];
    __shared__ float qbuf[3];
    const int b   = blockIdx.x;
    const int tid = threadIdx.x;
    const float* xb = xyz + (size_t)b * (NPTS * 3);

    float px[PPT], py[PPT], pz[PPT], md[PPT];
#pragma unroll
    for (int j = 0; j < PPT; ++j) {
        const int p = tid + FPS_T * j;
        px[j] = xb[p * 3 + 0];
        py[j] = xb[p * 3 + 1];
        pz[j] = xb[p * 3 + 2];
        md[j] = 1e10f;
    }

    if (tid < 16) slots[tid] = 0ull;

    float* newxyz = out;
    float* fpsidx = out + OFF_FPSIDX;

    if (tid == 0) {
        qbuf[0] = px[0]; qbuf[1] = py[0]; qbuf[2] = pz[0];
        fpsidx[(size_t)b * SPTS + 0] = 0.0f;
        newxyz[(size_t)b * SPTS * 3 + 0] = px[0];
        newxyz[(size_t)b * SPTS * 3 + 1] = py[0];
        newxyz[(size_t)b * SPTS * 3 + 2] = pz[0];
    }
    __syncthreads();

    for (int i = 1; i < SPTS; ++i) {
        const float qx = qbuf[0], qy = qbuf[1], qz = qbuf[2];

        // min-dist update: exact numpy order, no fma (contract off)
#pragma unroll
        for (int j = 0; j < PPT; ++j) {
            const float dx = px[j] - qx;
            const float dy = py[j] - qy;
            const float dz = pz[j] - qz;
            const float d  = (dx * dx + dy * dy) + dz * dz;
            md[j] = fminf(md[j], d);
        }
        // thread-local max (tree -> compiler emits v_max3)
        float best = md[0];
#pragma unroll
        for (int j = 1; j < PPT; ++j) best = fmaxf(best, md[j]);
        // smallest owned slot j with md[j]==best (descending overwrite)
        int bj = PPT - 1;
#pragma unroll
        for (int j = PPT - 2; j >= 0; --j) if (md[j] == best) bj = j;
        int bidx = tid + (bj << FPS_SHIFT);

        // 64-lane butterfly argmax, tie -> smallest index (matches jnp.argmax)
#pragma unroll
        for (int off = 32; off > 0; off >>= 1) {
            const float ov = __shfl_xor(best, off);
            const int   oi = __shfl_xor(bidx, off);
            if (ov > best || (ov == best && oi < bidx)) { best = ov; bidx = oi; }
        }
        if ((tid & 63) == 0) {
            const unsigned long long pk =
                ((unsigned long long)__float_as_uint(best) << 32) |
                (unsigned)(NPTS - bidx);   // larger packed = larger d, then smaller idx
            atomicMax(&slots[i & 15], pk);
        }
        // reset the slot that will be used 8 iterations from now (its last
        // readers finished >=7 barriers ago; next atomics >=7 barriers away)
        if (tid == 0) slots[(i + 8) & 15] = 0ull;
        __syncthreads();   // #1: all wave atomics for iter i complete

        const unsigned long long pk = slots[i & 15];
        const int widx = NPTS - (int)(unsigned)(pk & 0xffffffffull);
        if (tid == (widx & (FPS_T - 1))) {
            const int j = widx >> FPS_SHIFT;
            qbuf[0] = px[j]; qbuf[1] = py[j]; qbuf[2] = pz[j];
            fpsidx[(size_t)b * SPTS + i] = (float)widx;
            const size_t o = ((size_t)b * SPTS + i) * 3;
            newxyz[o + 0] = px[j]; newxyz[o + 1] = py[j]; newxyz[o + 2] = pz[j];
        }
        __syncthreads();   // #2: qbuf visible for next iteration
    }
}

// ---------------- ball query + grouping: one wave per center ----------------
__global__ __launch_bounds__(256)
void ballgroup_kernel(const float* __restrict__ xyz, const float* __restrict__ feat,
                      float* out)
{
#pragma clang fp contract(off)
    __shared__ int idxl[4][KS];
    const int tid    = threadIdx.x;
    const int wv     = tid >> 6;
    const int lane   = tid & 63;
    const int center = blockIdx.x * 4 + wv;
    const int b      = center >> 11;          // / SPTS
    const int s      = center & (SPTS - 1);
    const float* xb  = xyz + (size_t)b * (NPTS * 3);
    const float* newxyz = out;                // written by fps_kernel earlier in stream
    const float cx = newxyz[(size_t)center * 3 + 0];
    const float cy = newxyz[(size_t)center * 3 + 1];
    const float cz = newxyz[(size_t)center * 3 + 2];

    if (lane == 0) idxl[wv][0] = 0;           // default when zero hits

    int cnt = 0;
    for (int nb = 0; nb < NPTS; nb += 64) {
        const int p = nb + lane;
        const float x = xb[p * 3 + 0];
        const float y = xb[p * 3 + 1];
        const float z = xb[p * 3 + 2];
        const float dx = cx - x, dy = cy - y, dz = cz - z;
        const float d2 = (dx * dx + dy * dy) + dz * dz;
        // f32 'd2 <= 0.04f' == numpy 'f32 d2 < float64(0.2*0.2)' (see analysis)
        const bool in = (d2 <= 0.04f);
        const unsigned long long mk = __ballot(in);
        if (in) {
            const int pos = cnt + __popcll(mk & ((1ull << lane) - 1ull));
            if (pos < KS) idxl[wv][pos] = p;
        }
        cnt += (int)__popcll(mk);
        if (cnt >= KS) break;                 // cnt is wave-uniform
    }
    const int cc = cnt < KS ? cnt : KS;

    // pad short lists with first hit (or 0), write padded list back
    int myidx = 0;
    if (lane < KS) {
        myidx = (lane < cc) ? idxl[wv][lane] : idxl[wv][0];
        idxl[wv][lane] = myidx;
    }

    float* grouped = out + OFF_GROUPED;
    const size_t chstride = (size_t)SPTS * KS;                    // 65536
    const size_t base67   = (size_t)b * 67 * chstride + (size_t)s * KS;

    // channels 0..2: recentered coords (point - center)
    if (lane < KS) {
        const float gx = xb[(size_t)myidx * 3 + 0] - cx;
        const float gy = xb[(size_t)myidx * 3 + 1] - cy;
        const float gz = xb[(size_t)myidx * 3 + 2] - cz;
        grouped[base67 + 0 * chstride + lane] = gx;
        grouped[base67 + 1 * chstride + lane] = gy;
        grouped[base67 + 2 * chstride + lane] = gz;
    }

    // channels 3..66: feature gather; lanes = (k, c-half)
    const int k    = lane & (KS - 1);
    const int half = lane >> 5;
    const int gi   = idxl[wv][k];
    const float* fb = feat + (size_t)b * CF * NPTS;
    const size_t obase = base67 + 3 * chstride + (size_t)k;
#pragma unroll 8
    for (int c0 = 0; c0 < 32; ++c0) {
        const int c = c0 * 2 + half;
        grouped[obase + (size_t)c * chstride] = fb[(size_t)c * NPTS + gi];
    }
}

extern "C" void kernel_launch(void* const* d_in, const int* in_sizes, int n_in,
                              void* d_out, int out_size, void* d_ws, size_t ws_size,
                              hipStream_t stream) {
    const float* xyz  = (const float*)d_in[0];
    const float* feat = (const float*)d_in[1];
    float* out = (float*)d_out;
    fps_kernel<<<dim3(BQ), dim3(FPS_T), 0, stream>>>(xyz, out);
    ballgroup_kernel<<<dim3((BQ * SPTS) / 4), dim3(256), 0, stream>>>(xyz, feat, out);
}

// Round 2
// 2546.105 us; speedup vs baseline: 1.3650x; 1.3650x over previous
//
#include <hip/hip_runtime.h>

#define NPTS 8192
#define SPTS 2048
#define KS 32
#define CF 64
#define BQ 4
#define FPS_T 512
#define PPT (NPTS / FPS_T)   // 16 points per thread
#define FPS_SHIFT 9          // log2(FPS_T)

#define OFF_GROUPED 24576                    // B*S*3
#define GROUPED_SZ  17563648                 // B*67*S*K
#define OFF_FPSIDX  (OFF_GROUPED + GROUPED_SZ)

typedef __attribute__((ext_vector_type(2))) float vf2;
typedef unsigned long long u64;

// ---------------- FPS: one block per batch, 1 barrier per iteration ----------------
__global__ __launch_bounds__(FPS_T)
void fps_kernel(const float* __restrict__ xyz, float* __restrict__ out)
{
#pragma clang fp contract(off)
    __shared__ u64 slots[2][8];          // parity double-buffer; one slot per wave
    const int b    = blockIdx.x;
    const int tid  = threadIdx.x;
    const int wv   = tid >> 6;
    const int lane = tid & 63;
    const float* xb = xyz + (size_t)b * (NPTS * 3);

    vf2 pxy[PPT]; float pz[PPT], md[PPT];
#pragma unroll
    for (int j = 0; j < PPT; ++j) {
        const int p = tid + FPS_T * j;
        vf2 v; v.x = xb[p * 3 + 0]; v.y = xb[p * 3 + 1];
        pxy[j] = v;
        pz[j]  = xb[p * 3 + 2];
        md[j]  = 1e10f;
    }

    float* newxyz = out;
    float* fpsidx = out + OFF_FPSIDX;

    // iteration 0: center = point 0 (broadcast load from global)
    float qx = xb[0], qy = xb[1], qz = xb[2];
    if (tid == 0) {
        fpsidx[(size_t)b * SPTS + 0] = 0.0f;
        newxyz[(size_t)b * SPTS * 3 + 0] = qx;
        newxyz[(size_t)b * SPTS * 3 + 1] = qy;
        newxyz[(size_t)b * SPTS * 3 + 2] = qz;
    }

    for (int i = 1; i < SPTS; ++i) {
        vf2 q; q.x = qx; q.y = qy;

        // min-dist update: exact numpy rounding order (dx*dx+dy*dy)+dz*dz, no fma
#pragma unroll
        for (int j = 0; j < PPT; ++j) {
            const vf2 dxy = pxy[j] - q;        // v_pk_add_f32 (neg)
            const vf2 sq  = dxy * dxy;         // v_pk_mul_f32
            const float dz = pz[j] - qz;
            const float d  = (sq.x + sq.y) + dz * dz;
            md[j] = fminf(md[j], d);
        }

        // log-depth fmax tree over 16
        float t0 = fmaxf(md[0], md[1]),   t1 = fmaxf(md[2], md[3]);
        float t2 = fmaxf(md[4], md[5]),   t3 = fmaxf(md[6], md[7]);
        float t4 = fmaxf(md[8], md[9]),   t5 = fmaxf(md[10], md[11]);
        float t6 = fmaxf(md[12], md[13]), t7 = fmaxf(md[14], md[15]);
        t0 = fmaxf(t0, t1); t2 = fmaxf(t2, t3); t4 = fmaxf(t4, t5); t6 = fmaxf(t6, t7);
        t0 = fmaxf(t0, t2); t4 = fmaxf(t4, t6);
        const float best = fmaxf(t0, t4);

        // smallest owned j with md[j]==best (descending overwrite -> first max)
        int bj = PPT - 1;
#pragma unroll
        for (int j = PPT - 2; j >= 0; --j) if (md[j] == best) bj = j;
        const int bidx = tid + (bj << FPS_SHIFT);

        // pack (dist_bits, 8191-idx): u64 max == argmax dist, tie -> smaller idx
        u64 pk = ((u64)__float_as_uint(best) << 32) | (unsigned)(NPTS - 1 - bidx);

        // 64-lane butterfly max on packed key
#pragma unroll
        for (int off = 32; off > 0; off >>= 1) {
            const u64 o = __shfl_xor(pk, off);
            if (o > pk) pk = o;
        }
        if (lane == 0) slots[i & 1][wv] = pk;
        __syncthreads();                      // the only barrier per iteration

        // cross-wave reduce: 8 broadcast LDS reads + 7 compares (every thread)
        u64 g = slots[i & 1][0];
#pragma unroll
        for (int w = 1; w < 8; ++w) {
            const u64 s = slots[i & 1][w];
            if (s > g) g = s;
        }
        const int widx = (NPTS - 1) - (int)(unsigned)(g & 0xffffffffull);

        // winner coords: broadcast load from global (L2-hot), no 2nd barrier
        qx = xb[widx * 3 + 0];
        qy = xb[widx * 3 + 1];
        qz = xb[widx * 3 + 2];

        if (tid == 0) {
            fpsidx[(size_t)b * SPTS + i] = (float)widx;
            const size_t o = ((size_t)b * SPTS + i) * 3;
            newxyz[o + 0] = qx; newxyz[o + 1] = qy; newxyz[o + 2] = qz;
        }
    }
}

// ---------------- ball query + grouping: one wave per center ----------------
__global__ __launch_bounds__(256)
void ballgroup_kernel(const float* __restrict__ xyz, const float* __restrict__ feat,
                      float* out)
{
#pragma clang fp contract(off)
    __shared__ int idxl[4][KS];
    const int tid    = threadIdx.x;
    const int wv     = tid >> 6;
    const int lane   = tid & 63;
    const int center = blockIdx.x * 4 + wv;
    const int b      = center >> 11;          // / SPTS
    const int s      = center & (SPTS - 1);
    const float* xb  = xyz + (size_t)b * (NPTS * 3);
    const float* newxyz = out;                // written by fps_kernel earlier in stream
    const float cx = newxyz[(size_t)center * 3 + 0];
    const float cy = newxyz[(size_t)center * 3 + 1];
    const float cz = newxyz[(size_t)center * 3 + 2];

    if (lane == 0) idxl[wv][0] = 0;           // default when zero hits

    int cnt = 0;
    for (int nb = 0; nb < NPTS; nb += 64) {
        const int p = nb + lane;
        const float x = xb[p * 3 + 0];
        const float y = xb[p * 3 + 1];
        const float z = xb[p * 3 + 2];
        const float dx = cx - x, dy = cy - y, dz = cz - z;
        const float d2 = (dx * dx + dy * dy) + dz * dz;
        // f32 'd2 <= 0.04f' == numpy 'f32 d2 < float64(0.2*0.2)'
        const bool in = (d2 <= 0.04f);
        const unsigned long long mk = __ballot(in);
        if (in) {
            const int pos = cnt + __popcll(mk & ((1ull << lane) - 1ull));
            if (pos < KS) idxl[wv][pos] = p;
        }
        cnt += (int)__popcll(mk);
        if (cnt >= KS) break;                 // cnt is wave-uniform
    }
    const int cc = cnt < KS ? cnt : KS;

    // pad short lists with first hit (or 0), write padded list back
    int myidx = 0;
    if (lane < KS) {
        myidx = (lane < cc) ? idxl[wv][lane] : idxl[wv][0];
        idxl[wv][lane] = myidx;
    }

    float* grouped = out + OFF_GROUPED;
    const size_t chstride = (size_t)SPTS * KS;                    // 65536
    const size_t base67   = (size_t)b * 67 * chstride + (size_t)s * KS;

    // channels 0..2: recentered coords (point - center)
    if (lane < KS) {
        const float gx = xb[(size_t)myidx * 3 + 0] - cx;
        const float gy = xb[(size_t)myidx * 3 + 1] - cy;
        const float gz = xb[(size_t)myidx * 3 + 2] - cz;
        grouped[base67 + 0 * chstride + lane] = gx;
        grouped[base67 + 1 * chstride + lane] = gy;
        grouped[base67 + 2 * chstride + lane] = gz;
    }

    // channels 3..66: feature gather; lanes = (k, c-half)
    const int k    = lane & (KS - 1);
    const int half = lane >> 5;
    const int gi   = idxl[wv][k];
    const float* fb = feat + (size_t)b * CF * NPTS;
    const size_t obase = base67 + 3 * chstride + (size_t)k;
#pragma unroll 8
    for (int c0 = 0; c0 < 32; ++c0) {
        const int c = c0 * 2 + half;
        grouped[obase + (size_t)c * chstride] = fb[(size_t)c * NPTS + gi];
    }
}

extern "C" void kernel_launch(void* const* d_in, const int* in_sizes, int n_in,
                              void* d_out, int out_size, void* d_ws, size_t ws_size,
                              hipStream_t stream) {
    const float* xyz  = (const float*)d_in[0];
    const float* feat = (const float*)d_in[1];
    float* out = (float*)d_out;
    fps_kernel<<<dim3(BQ), dim3(FPS_T), 0, stream>>>(xyz, out);
    ballgroup_kernel<<<dim3((BQ * SPTS) / 4), dim3(256), 0, stream>>>(xyz, feat, out);
}